// Round 4
// baseline (1182.928 us; speedup 1.0000x reference)
//
#include <hip/hip_runtime.h>

#define DI __device__ __forceinline__

typedef __attribute__((ext_vector_type(8))) short short8;
typedef __attribute__((ext_vector_type(4))) float f32x4;

constexpr int THREADS = 512;           // 8 waves
constexpr int ROWS    = 16;            // batch rows per block
constexpr int NBLK    = 8192 / ROWS;   // 512 blocks -> 2 blocks/CU
constexpr int PITCH_H  = 272;          // h rows (K=128 bf16): 68 dw, 2-way banks
constexpr int PITCH_X  = 264;          // x rows: 66 dw, 2-way banks
constexpr int PITCH_GI = 776;          // gi rows (384 cols bf16 + pad): 194 dw
constexpr int PITCH_A1 = 528;          // K=256 bf16 rows
constexpr int SPITCH   = 256;          // one-time staging pitch

// ---- LDS layout (bytes) ----
constexpr int O_PATCH = 0;        // 5120:  64 rows x 80B (4 steps x 16 rows)
constexpr int O_XALL  = 5120;     // 16896: 64 rows x 264B
constexpr int O_GI    = 22016;    // 49664: 64 rows x 776B  -> encoder region ends 71680
// decoder aliases (same region):
constexpr int O_A1D   = 0;        // 8448:  16 x 528
constexpr int O_A2D   = 8448;     // 2304:  16 x 144
constexpr int O_FC2   = 10752;    // 33792: 64 x 528 (resident all decoder)
constexpr int O_H     = 71680;    // 2 x 4352 hidden-state double buffer
constexpr int HBUF    = 4352;
constexpr int O_FC3W  = 80384;    // 1536: fc3 weights f32
constexpr int LDS_TOTAL = 81920;  // exactly half of 160 KiB -> 2 blocks/CU

DI unsigned short f2bf(float f){
  union { float f; unsigned u; } v; v.f = f;
  return (unsigned short)((v.u + 0x7fffu + ((v.u >> 16) & 1u)) >> 16);
}
DI float bf2f(unsigned short u){
  union { unsigned u; float f; } v; v.u = ((unsigned)u) << 16;
  return v.f;
}
DI float sigm(float x){ return 1.f / (1.f + __expf(-x)); }
DI float tanh_(float x){
  float ax = fabsf(x);
  float e = __expf(-2.f * ax);
  float t = (1.f - e) / (1.f + e);
  return copysignf(t, x);
}
DI f32x4 mfma16(short8 a, short8 b, f32x4 c){
  return __builtin_amdgcn_mfma_f32_16x16x32_bf16(a, b, c, 0, 0, 0);
}

// one-time: stage (nrows x 128) f32 -> bf16 LDS at pitch SPITCH (nrows <= 128)
DI void stage_k128(char* dst, const float* __restrict__ src, int nrows, int tid){
  const int total = nrows * 32;
  for (int i = tid; i < total; i += THREADS){
    float4 v = ((const float4*)src)[i];
    int e = i << 2;
    int n = e >> 7, k = e & 127;
    unsigned lo = (unsigned)f2bf(v.x) | ((unsigned)f2bf(v.y) << 16);
    unsigned hi = (unsigned)f2bf(v.z) | ((unsigned)f2bf(v.w) << 16);
    *(uint2*)(dst + n * SPITCH + k * 2) = make_uint2(lo, hi);
  }
}
// one-time: stage (nrows x 256) f32 -> bf16 LDS, pitch 528
DI void stage_k256(char* dst, const float* __restrict__ src, int nrows, int tid){
  const int total = nrows * 64;
  for (int i = tid; i < total; i += THREADS){
    float4 v = ((const float4*)src)[i];
    int e = i << 2;
    int n = e >> 8, k = e & 255;
    unsigned lo = (unsigned)f2bf(v.x) | ((unsigned)f2bf(v.y) << 16);
    unsigned hi = (unsigned)f2bf(v.z) | ((unsigned)f2bf(v.w) << 16);
    *(uint2*)(dst + n * PITCH_A1 + k * 2) = make_uint2(lo, hi);
  }
}

__global__ void __launch_bounds__(THREADS, 4)
gru_fused(const float* __restrict__ past,
          const float* __restrict__ conv_w, const float* __restrict__ conv_b,
          const float* __restrict__ bn_gamma, const float* __restrict__ bn_beta,
          const float* __restrict__ bn_mean, const float* __restrict__ bn_var,
          const float* __restrict__ enc_wih, const float* __restrict__ enc_whh,
          const float* __restrict__ enc_bih, const float* __restrict__ enc_bhh,
          const float* __restrict__ dec_wih, const float* __restrict__ dec_whh,
          const float* __restrict__ dec_bih, const float* __restrict__ dec_bhh,
          const float* __restrict__ fc1_w, const float* __restrict__ fc1_b,
          const float* __restrict__ fc2_w, const float* __restrict__ fc2_b,
          const float* __restrict__ fc3_w, const float* __restrict__ fc3_b,
          float* __restrict__ out)
{
  extern __shared__ char smem[];
  const int tid  = threadIdx.x;
  const int lane = tid & 63, w = tid >> 6;        // wave w owns gate-col slice w*16..
  const int l15  = lane & 15, quad = lane >> 4;
  const int b0   = blockIdx.x * ROWS;
  const int col  = w * 16 + l15;
  const float* pbase = past + (size_t)b0 * 768;

  // ---- encoder-phase scalar constants ----
  const float br_e  = enc_bih[col]       + enc_bhh[col];        // folded into gi
  const float bz_e  = enc_bih[128 + col] + enc_bhh[128 + col];
  const float bin_e = enc_bih[256 + col];
  const float bhn_e = enc_bhh[256 + col];
  const float cb_t  = conv_b[col];
  const float s_bn  = bn_gamma[0] * rsqrtf(bn_var[0] + 1e-5f);
  const float o_bn  = bn_beta[0] - bn_mean[0] * s_bn;

  // ---- zero h double buffer ----
  for (int i = tid; i < 2*HBUF/4; i += THREADS) ((unsigned*)(smem + O_H))[i] = 0u;
  for (int i = tid; i < 384; i += THREADS) ((float*)(smem + O_FC3W))[i] = fc3_w[i];

  // ---- stage encoder weights (3 passes of 128 rows = one gate per pass) ----
  short8 wf[3][4], wh[3][4];
  #pragma unroll
  for (int g = 0; g < 3; ++g){
    __syncthreads();
    stage_k128(smem, enc_wih + g*128*128, 128, tid);
    __syncthreads();
    #pragma unroll
    for (int kt = 0; kt < 4; ++kt)
      wf[g][kt] = *(const short8*)(smem + col*SPITCH + kt*64 + quad*16);
  }
  #pragma unroll
  for (int g = 0; g < 3; ++g){
    __syncthreads();
    stage_k128(smem, enc_whh + g*128*128, 128, tid);
    __syncthreads();
    #pragma unroll
    for (int kt = 0; kt < 4; ++kt)
      wh[g][kt] = *(const short8*)(smem + col*SPITCH + kt*64 + quad*16);
  }
  __syncthreads();

  // ---- conv weights: cwT[oc][k=c*3+kk] bf16, 80B rows, K padded 18->32 ----
  for (int i = tid; i < 2560; i += THREADS) ((unsigned*)smem)[i] = 0u;
  __syncthreads();
  for (int i = tid; i < 2304; i += THREADS){
    int oc = i / 18, kk = i - oc * 18;
    *(unsigned short*)(smem + oc*80 + kk*2) = f2bf(conv_w[i]);
  }
  __syncthreads();
  const short8 cwf = *(const short8*)(smem + col*80 + quad*16);
  __syncthreads();

  float hreg[4];
  #pragma unroll
  for (int i = 0; i < 4; ++i) hreg[i] = 0.f;

  // ================= encoder: 32 chunks of (A-phases + 4 light steps) =================
  for (int chunk = 0; chunk < 32; ++chunk){
    const int t0 = chunk * 4;
    // ---- A1: build 64-row patch straight from global past (L2-resident) ----
    for (int e = tid; e < 1152; e += THREADS){
      int row = e / 18, r18 = e - row*18;
      int m16 = row & 15, tcs = row >> 4;
      int c = r18 / 3, kk = r18 - c*3;
      int tin = t0 + tcs - 1 + kk;
      float v = (tin >= 0 && tin < 128) ? pbase[(size_t)m16*768 + c*128 + tin] : 0.f;
      *(unsigned short*)(smem + O_PATCH + row*80 + r18*2) = f2bf(v);
    }
    __syncthreads();
    // ---- A2: conv as M=64 GEMM + bias/relu/bn -> x_all ----
    #pragma unroll
    for (int mt8 = 0; mt8 < 4; ++mt8){
      short8 pa = *(const short8*)(smem + O_PATCH + (mt8*16 + l15)*80 + quad*16);
      f32x4 cc = (f32x4){0.f,0.f,0.f,0.f};
      cc = mfma16(pa, cwf, cc);
      #pragma unroll
      for (int r = 0; r < 4; ++r){
        int mrow = mt8*16 + quad*4 + r;
        float vx = s_bn * fmaxf(cc[r] + cb_t, 0.f) + o_bn;
        *(unsigned short*)(smem + O_XALL + mrow*PITCH_X + col*2) = f2bf(vx);
      }
    }
    __syncthreads();
    // ---- A3: gi GEMM for 4 steps + full bias fold -> gi LDS (bf16) ----
    #pragma unroll
    for (int tc = 0; tc < 4; ++tc){
      short8 a[4];
      #pragma unroll
      for (int kt = 0; kt < 4; ++kt)
        a[kt] = *(const short8*)(smem + O_XALL + (tc*16 + l15)*PITCH_X + kt*64 + quad*16);
      f32x4 gr = (f32x4){0.f,0.f,0.f,0.f}, gz = gr, gn = gr;
      #pragma unroll
      for (int kt = 0; kt < 4; ++kt){
        gr = mfma16(a[kt], wf[0][kt], gr);
        gz = mfma16(a[kt], wf[1][kt], gz);
        gn = mfma16(a[kt], wf[2][kt], gn);
      }
      #pragma unroll
      for (int r = 0; r < 4; ++r){
        char* grow = smem + O_GI + (tc*16 + quad*4 + r)*PITCH_GI;
        *(unsigned short*)(grow + col*2)         = f2bf(gr[r] + br_e);
        *(unsigned short*)(grow + (128+col)*2)   = f2bf(gz[r] + bz_e);
        *(unsigned short*)(grow + (256+col)*2)   = f2bf(gn[r] + bin_e);
      }
    }
    __syncthreads();
    // ---- 4 recurrent steps: gh GEMM + gate math, 1 barrier each ----
    #pragma unroll
    for (int tc = 0; tc < 4; ++tc){
      const int t = t0 + tc;
      const char* hr = smem + O_H + (t & 1) * HBUF;
      char*       hw = smem + O_H + ((t + 1) & 1) * HBUF;
      short8 ha[4];
      #pragma unroll
      for (int kt = 0; kt < 4; ++kt)
        ha[kt] = *(const short8*)(hr + l15*PITCH_H + kt*64 + quad*16);
      f32x4 ar, az, an = (f32x4){0.f,0.f,0.f,0.f};
      f32x4 gin;
      #pragma unroll
      for (int r = 0; r < 4; ++r){
        const char* grow = smem + O_GI + (tc*16 + quad*4 + r)*PITCH_GI;
        ar[r]  = bf2f(*(const unsigned short*)(grow + col*2));
        az[r]  = bf2f(*(const unsigned short*)(grow + (128+col)*2));
        gin[r] = bf2f(*(const unsigned short*)(grow + (256+col)*2));
      }
      #pragma unroll
      for (int kt = 0; kt < 4; ++kt){
        ar = mfma16(ha[kt], wh[0][kt], ar);
        az = mfma16(ha[kt], wh[1][kt], az);
        an = mfma16(ha[kt], wh[2][kt], an);
      }
      #pragma unroll
      for (int r = 0; r < 4; ++r){
        float rg = sigm(ar[r]);
        float zg = sigm(az[r]);
        float ng = tanh_(gin[r] + rg*(an[r] + bhn_e));
        hreg[r] = ng + zg*(hreg[r] - ng);
      }
      #pragma unroll
      for (int r = 0; r < 4; ++r)
        *(unsigned short*)(hw + (quad*4 + r)*PITCH_H + col*2) = f2bf(hreg[r]);
      __syncthreads();   // h(t+1) visible; h(t)/gi reads done
    }
  }
  // h_enc now in hbuf[0] (t=127 wrote (128)&1 = 0)

  // ================= decoder init =================
  // dec_wih frags (reuse wf) + gi0 = h_enc @ dec_wih^T
  #pragma unroll
  for (int g = 0; g < 3; ++g){
    __syncthreads();
    stage_k128(smem, dec_wih + g*128*128, 128, tid);
    __syncthreads();
    #pragma unroll
    for (int kt = 0; kt < 4; ++kt)
      wf[g][kt] = *(const short8*)(smem + col*SPITCH + kt*64 + quad*16);
  }
  f32x4 gi0r, gi0z, gi0n;
  {
    short8 hea[4];
    #pragma unroll
    for (int kt = 0; kt < 4; ++kt)
      hea[kt] = *(const short8*)(smem + O_H + l15*PITCH_H + kt*64 + quad*16);
    gi0r = (f32x4){0.f,0.f,0.f,0.f}; gi0z = gi0r; gi0n = gi0r;
    #pragma unroll
    for (int kt = 0; kt < 4; ++kt){
      gi0r = mfma16(hea[kt], wf[0][kt], gi0r);
      gi0z = mfma16(hea[kt], wf[1][kt], gi0z);
      gi0n = mfma16(hea[kt], wf[2][kt], gi0n);
    }
  }
  // dec_whh frags (reuse wh)
  #pragma unroll
  for (int g = 0; g < 3; ++g){
    __syncthreads();
    stage_k128(smem, dec_whh + g*128*128, 128, tid);
    __syncthreads();
    #pragma unroll
    for (int kt = 0; kt < 4; ++kt)
      wh[g][kt] = *(const short8*)(smem + col*SPITCH + kt*64 + quad*16);
  }
  // fc1 frags (2 passes of 128 rows); wave w pulls when its rows are staged
  short8 f1f[2][4];
  #pragma unroll
  for (int p = 0; p < 2; ++p){
    __syncthreads();
    stage_k128(smem, fc1_w + p*128*128, 128, tid);
    __syncthreads();
    if ((w >> 2) == p){
      #pragma unroll
      for (int j = 0; j < 2; ++j)
        #pragma unroll
        for (int kt = 0; kt < 4; ++kt)
          f1f[j][kt] = *(const short8*)(smem + ((w & 3)*32 + j*16 + l15)*SPITCH +
                                        kt*64 + quad*16);
    }
  }
  __syncthreads();
  stage_k256(smem + O_FC2, fc2_w, 64, tid);   // fc2 resident in LDS all decoder
  // decoder scalar constants (loaded late to keep encoder reg pressure low)
  const float br_d  = dec_bih[col]       + dec_bhh[col];
  const float bz_d  = dec_bih[128 + col] + dec_bhh[128 + col];
  const float bin_d = dec_bih[256 + col];
  const float bhn_d = dec_bhh[256 + col];
  const float fb1a  = fc1_b[w * 32 + l15];
  const float fb1b  = fc1_b[w * 32 + 16 + l15];
  const float fb2   = (w < 4) ? fc2_b[w * 16 + l15] : 0.f;
  const int prow = tid / 6, pcol = tid - prow*6;
  float present = 0.f, fb3 = 0.f;
  if (tid < 96){
    present = pbase[(size_t)prow*768 + pcol*128 + 127];
    fb3 = fc3_b[pcol];
  }
  // zero hbuf[1] = decoder h0
  for (int i = tid; i < HBUF/4; i += THREADS) ((unsigned*)(smem + O_H + HBUF))[i] = 0u;
  #pragma unroll
  for (int i = 0; i < 4; ++i) hreg[i] = 0.f;
  __syncthreads();

  // ================= decoder: 30 steps, 3 barriers each =================
  for (int s = 0; s < 30; ++s){
    const char* hr = smem + O_H + (1 - (s & 1)) * HBUF;
    char*       hw = smem + O_H + (s & 1) * HBUF;
    f32x4 ar, az, an = (f32x4){0.f,0.f,0.f,0.f};
    f32x4 gin;
    if (s == 0){
      #pragma unroll
      for (int r = 0; r < 4; ++r){
        ar[r] = gi0r[r] + br_d; az[r] = gi0z[r] + bz_d; gin[r] = gi0n[r] + bin_d;
      }
    } else {
      #pragma unroll
      for (int r = 0; r < 4; ++r){ ar[r] = br_d; az[r] = bz_d; gin[r] = bin_d; }
    }
    {
      short8 ha[4];
      #pragma unroll
      for (int kt = 0; kt < 4; ++kt)
        ha[kt] = *(const short8*)(hr + l15*PITCH_H + kt*64 + quad*16);
      #pragma unroll
      for (int kt = 0; kt < 4; ++kt){
        ar = mfma16(ha[kt], wh[0][kt], ar);
        az = mfma16(ha[kt], wh[1][kt], az);
        an = mfma16(ha[kt], wh[2][kt], an);
      }
    }
    #pragma unroll
    for (int r = 0; r < 4; ++r){
      float rg = sigm(ar[r]);
      float zg = sigm(az[r]);
      float ng = tanh_(gin[r] + rg*(an[r] + bhn_d));
      hreg[r] = ng + zg*(hreg[r] - ng);
    }
    #pragma unroll
    for (int r = 0; r < 4; ++r)
      *(unsigned short*)(hw + (quad*4 + r)*PITCH_H + col*2) = f2bf(hreg[r]);
    __syncthreads();   // D1: h(s+1) visible

    // fc1: (16x128)@(128x256) + relu -> a1
    {
      short8 hf[4];
      #pragma unroll
      for (int kt = 0; kt < 4; ++kt)
        hf[kt] = *(const short8*)(hw + l15*PITCH_H + kt*64 + quad*16);
      f32x4 a1a[2];
      a1a[0] = (f32x4){0.f,0.f,0.f,0.f}; a1a[1] = a1a[0];
      #pragma unroll
      for (int j = 0; j < 2; ++j)
        #pragma unroll
        for (int kt = 0; kt < 4; ++kt)
          a1a[j] = mfma16(hf[kt], f1f[j][kt], a1a[j]);
      #pragma unroll
      for (int j = 0; j < 2; ++j){
        float bb = j ? fb1b : fb1a;
        #pragma unroll
        for (int r = 0; r < 4; ++r)
          *(unsigned short*)(smem + O_A1D + (quad*4 + r)*PITCH_A1 +
                             (w*32 + j*16 + l15)*2) = f2bf(fmaxf(a1a[j][r] + bb, 0.f));
      }
    }
    __syncthreads();   // D2: a1 visible

    // fc2: (16x256)@(256x64) -> a2 (waves 0-3)
    if (w < 4){
      f32x4 a2a = (f32x4){0.f,0.f,0.f,0.f};
      #pragma unroll
      for (int kt = 0; kt < 8; ++kt){
        short8 a = *(const short8*)(smem + O_A1D + l15*PITCH_A1 + kt*64 + quad*16);
        short8 b = *(const short8*)(smem + O_FC2 + (w*16 + l15)*PITCH_A1 + kt*64 + quad*16);
        a2a = mfma16(a, b, a2a);
      }
      #pragma unroll
      for (int r = 0; r < 4; ++r)
        *(unsigned short*)(smem + O_A2D + (quad*4 + r)*144 + (w*16 + l15)*2) =
            f2bf(a2a[r] + fb2);
    }
    __syncthreads();   // D3: a2 visible

    // fc3 (6x64, VALU) + present accumulate + store
    if (tid < 96){
      float o = fb3;
      const float* w3 = (const float*)(smem + O_FC3W) + pcol*64;
      #pragma unroll
      for (int kc = 0; kc < 8; ++kc){
        short8 av = *(const short8*)(smem + O_A2D + prow*144 + kc*16);
        #pragma unroll
        for (int j = 0; j < 8; ++j)
          o += bf2f((unsigned short)av[j]) * w3[kc*8 + j];
      }
      present += o;
      out[(size_t)(b0 + prow)*180 + pcol*30 + s] = present;   // (B, 6, 30)
    }
    // fc3's a2 reads protected by next step's D1/D2 barriers
  }
}

extern "C" void kernel_launch(void* const* d_in, const int* in_sizes, int n_in,
                              void* d_out, int out_size, void* d_ws, size_t ws_size,
                              hipStream_t stream) {
  (void)in_sizes; (void)n_in; (void)out_size; (void)d_ws; (void)ws_size;
  const float* past     = (const float*)d_in[0];
  const float* conv_w   = (const float*)d_in[1];
  const float* conv_b   = (const float*)d_in[2];
  const float* bn_gamma = (const float*)d_in[3];
  const float* bn_beta  = (const float*)d_in[4];
  const float* bn_mean  = (const float*)d_in[5];
  const float* bn_var   = (const float*)d_in[6];
  const float* enc_wih  = (const float*)d_in[7];
  const float* enc_whh  = (const float*)d_in[8];
  const float* enc_bih  = (const float*)d_in[9];
  const float* enc_bhh  = (const float*)d_in[10];
  const float* dec_wih  = (const float*)d_in[11];
  const float* dec_whh  = (const float*)d_in[12];
  const float* dec_bih  = (const float*)d_in[13];
  const float* dec_bhh  = (const float*)d_in[14];
  const float* fc1_w    = (const float*)d_in[15];
  const float* fc1_b    = (const float*)d_in[16];
  const float* fc2_w    = (const float*)d_in[17];
  const float* fc2_b    = (const float*)d_in[18];
  const float* fc3_w    = (const float*)d_in[19];
  const float* fc3_b    = (const float*)d_in[20];

  hipFuncSetAttribute((const void*)gru_fused,
                      hipFuncAttributeMaxDynamicSharedMemorySize, LDS_TOTAL);

  gru_fused<<<NBLK, THREADS, LDS_TOTAL, stream>>>(
      past, conv_w, conv_b, bn_gamma, bn_beta, bn_mean, bn_var,
      enc_wih, enc_whh, enc_bih, enc_bhh,
      dec_wih, dec_whh, dec_bih, dec_bhh,
      fc1_w, fc1_b, fc2_w, fc2_b, fc3_w, fc3_b,
      (float*)d_out);
}